// Round 22
// baseline (416.102 us; speedup 1.0000x reference)
//
#include <hip/hip_runtime.h>
#include <hip/hip_bf16.h>
#include <hip/hip_fp16.h>

// Problem constants (fixed by reference setup_inputs)
#define NN 100000
#define NE 1600000
#define ET 1700000   // NE + NN self loops
#define NEG_SLOPE 0.2f
#define EPSI 1e-16f

#define SCAN_NB 98
#define DEG_PAD (SCAN_NB * 1024)   // 100352

// Workspace layout (4-byte element offsets). Total ~25 MB.
#define OFF_AS2      1200032   // [NN]
#define OFF_ADI      1300032   // [NN float2: .x=ad2, .y=1/den2] (8B aligned)
#define OFF_XW2H     1500032   // [NN*32 halfs = NN*16 floats]
#define OFF_OFFS     3100032   // [NN+1] int
#define OFF_RANK     3200034   // [ET ushort = 850000 floats]
#define OFF_EDATA    4050034   // [ET] int
#define OFF_POOLPART 5750036   // [12500*32] (8B aligned)
#define OFF_DEG      6150036   // [DEG_PAD] int (16B aligned) -- zero zone
#define OFF_POOL     6250388   // [64]
#define OFF_BSUM     6250452   // [112]
#define ZERO_START   OFF_DEG
#define ZERO_N4      ((DEG_PAD + 64) / 4)   // 25104 float4 (deg + pool)

__device__ __forceinline__ float lrelu(float v) { return v > 0.f ? v : NEG_SLOPE * v; }

// Zero-fill (grid-stride; deg + pool)
__global__ void kz(float4* __restrict__ p, int n4) {
    int st = gridDim.x * 256;
    for (int i = blockIdx.x * 256 + threadIdx.x; i < n4; i += st)
        p[i] = make_float4(0.f, 0.f, 0.f, 0.f);
}

// CSR: degree histogram; atomic return value IS the edge's rank (max degree << 65536)
__global__ void kc1_deg(const int* __restrict__ ei, int* __restrict__ deg,
                        unsigned short* __restrict__ rank) {
    int e = blockIdx.x * 256 + threadIdx.x;
    if (e >= ET) return;
    int d_ = (e < NE) ? ei[NE + e] : (e - NE);
    rank[e] = (unsigned short)atomicAdd(&deg[d_], 1);
}

// Scan phase A: per-block (1024 elems) sums
__global__ void kc2a(const int* __restrict__ deg, int* __restrict__ bsum) {
    __shared__ int ws_[4];
    int b = blockIdx.x, t = threadIdx.x;
    int4 d = *(const int4*)(deg + b * 1024 + t * 4);
    int s = d.x + d.y + d.z + d.w;
#pragma unroll
    for (int m = 1; m < 64; m <<= 1) s += __shfl_xor(s, m);
    if ((t & 63) == 0) ws_[t >> 6] = s;
    __syncthreads();
    if (t == 0) bsum[b] = ws_[0] + ws_[1] + ws_[2] + ws_[3];
}

// Scan phase C: every block scans the 98 block sums, then intra-block
__global__ void kc2c(const int* __restrict__ deg, const int* __restrict__ bsum,
                     int* __restrict__ offs) {
    __shared__ int bs[128];
    __shared__ int ts[256];
    int b = blockIdx.x, t = threadIdx.x;
    if (t < 128) bs[t] = (t < SCAN_NB) ? bsum[t] : 0;
    __syncthreads();
    for (int off = 1; off < 128; off <<= 1) {
        int u = (t >= off && t < 128) ? bs[t - off] : 0;
        __syncthreads();
        if (t < 128) bs[t] += u;
        __syncthreads();
    }
    int bpre = (b == 0) ? 0 : bs[b - 1];
    int base = b * 1024 + t * 4;
    int4 d = *(const int4*)(deg + base);
    int s = d.x + d.y + d.z + d.w;
    ts[t] = s;
    __syncthreads();
    for (int off = 1; off < 256; off <<= 1) {
        int u = (t >= off) ? ts[t - off] : 0;
        __syncthreads();
        ts[t] += u;
        __syncthreads();
    }
    int r = bpre + ((t == 0) ? 0 : ts[t - 1]);
    if (base < NN)     offs[base] = r;     r += d.x;
    if (base + 1 < NN) offs[base + 1] = r; r += d.y;
    if (base + 2 < NN) offs[base + 2] = r; r += d.z;
    if (base + 3 < NN) offs[base + 3] = r;
    if (b == 0 && t == 0) offs[NN] = bs[SCAN_NB - 1];   // == ET
}

// CSR fill: NO atomic — position = offs[dst] + rank[e]
__global__ void kc3_fill(const int* __restrict__ ei, const int* __restrict__ offs,
                         const unsigned short* __restrict__ rank, int* __restrict__ edata) {
    int e = blockIdx.x * 256 + threadIdx.x;
    if (e >= ET) return;
    int s_, d_;
    if (e < NE) { s_ = ei[e]; d_ = ei[NE + e]; } else { s_ = d_ = e - NE; }
    edata[offs[d_] + (int)rank[e]] = s_;
}

// K4AB: fused conv1 gather + dense. att1 fold computed IN-REGISTER per wave
// (lane t computes fold entry t&31; shfl distributes) — k1 kernel eliminated;
// gather reads raw x (1.6 MB working set). W2 staged transposed in LDS.
__global__ __launch_bounds__(256) void k4ab(
    const int* __restrict__ offs, const int* __restrict__ edata,
    const float* __restrict__ x, const float* __restrict__ aS1,
    const float* __restrict__ aD1, const float* __restrict__ W1,
    const float* __restrict__ b1, const float* __restrict__ W2,
    const float* __restrict__ aw_s2, const float* __restrict__ aw_d2,
    __half* __restrict__ xw2h, float* __restrict__ as2, float* __restrict__ adi) {
    __shared__ float w2t[32][132];          // transposed W2, padded (16.9 KB)
    __shared__ float hs[4][128];
    int tid = threadIdx.x;
    int wv = tid >> 6, ln = tid & 63;
    int n = blockIdx.x * 4 + wv;            // grid exact: 25000*4 = NN
    // ---- stage W2^T into LDS (coalesced; overlaps with everything below) ----
    {
        int sf = tid & 31, sk0 = (tid >> 5) * 16;
#pragma unroll
        for (int j = 0; j < 16; j++)
            w2t[sf][sk0 + j] = W2[(sk0 + j) * 32 + sf];
    }
    // ---- in-register W1@att fold: entry u = fold(k=(u&15)>>2, h=u&3, src/dst) ----
    int hq = ln & 3, p = ln >> 2;
    {
        int u = ln & 31;
        int fk = (u & 15) >> 2, fh = u & 3;
        const float* av = (u < 16) ? aS1 : aD1;
        float fold = 0.f;
#pragma unroll
        for (int f = 0; f < 32; f++) fold += W1[fk * 128 + fh * 32 + f] * av[fh * 32 + f];
        // distribute: lane needs src-fold[k][hq] and dst-fold[k][hq], k=0..3
        float ws0 = __shfl(fold, hq),      ws1 = __shfl(fold, 4 + hq);
        float ws2 = __shfl(fold, 8 + hq),  ws3 = __shfl(fold, 12 + hq);
        float wd0 = __shfl(fold, 16 + hq), wd1 = __shfl(fold, 20 + hq);
        float wd2 = __shfl(fold, 24 + hq), wd3 = __shfl(fold, 28 + hq);
        float4 xn = *(const float4*)(x + n * 4);     // broadcast line
        float ad = xn.x * wd0 + xn.y * wd1 + xn.z * wd2 + xn.w * wd3;
        // ---- gather phase: ex = exp(lrelu(x[src]@ws + ad)) ----
        float z0 = 0.f, z1 = 0.f, z2 = 0.f, z3 = 0.f, den = 0.f;
        int beg = offs[n], end = offs[n + 1];
        for (int j = beg + p; j < end; j += 16) {
            int src = edata[j];
            float4 xv = *(const float4*)(x + src * 4);
            float e1 = xv.x * ws0 + xv.y * ws1 + xv.z * ws2 + xv.w * ws3;
            float ex = __expf(lrelu(e1 + ad));
            den += ex;
            z0 += ex * xv.x; z1 += ex * xv.y; z2 += ex * xv.z; z3 += ex * xv.w;
        }
#pragma unroll
        for (int m = 4; m <= 32; m <<= 1) {
            den += __shfl_xor(den, m);
            z0 += __shfl_xor(z0, m); z1 += __shfl_xor(z1, m);
            z2 += __shfl_xor(z2, m); z3 += __shfl_xor(z3, m);
        }
        float inv = 1.f / (den + EPSI);
        float v0 = z0 * inv, v1 = z1 * inv, v2 = z2 * inv, v3 = z3 * inv;
        // ---- W1 + elu (msg via shfl: head h lives in lane h) ----
        int f0 = ln * 2, h = ln >> 4;
        float mx = __shfl(v0, h), my = __shfl(v1, h), mz = __shfl(v2, h), mw = __shfl(v3, h);
        float h0 = mx * W1[f0]     + my * W1[128 + f0]     + mz * W1[256 + f0]     + mw * W1[384 + f0]     + b1[f0];
        float h1 = mx * W1[f0 + 1] + my * W1[128 + f0 + 1] + mz * W1[256 + f0 + 1] + mw * W1[384 + f0 + 1] + b1[f0 + 1];
        h0 = h0 > 0.f ? h0 : (__expf(h0) - 1.f);
        h1 = h1 > 0.f ? h1 : (__expf(h1) - 1.f);
        hs[wv][f0] = h0; hs[wv][f0 + 1] = h1;
    }
    __syncthreads();                        // covers w2t staging + hs
    // ---- dense: a[f] = sum_k h[k]*W2[k][f]; half splits k; LDS b128 reads ----
    int f = ln & 31, kb = (ln >> 5) * 64;
    const float* hrow = &hs[wv][kb];
    const float* wrow = &w2t[f][kb];
    float a0 = 0.f, a1 = 0.f;
#pragma unroll
    for (int k = 0; k < 64; k += 4) {
        float4 hv  = *(const float4*)(hrow + k);
        float4 wv4 = *(const float4*)(wrow + k);
        a0 += hv.x * wv4.x + hv.y * wv4.y;
        a1 += hv.z * wv4.z + hv.w * wv4.w;
    }
    float a = a0 + a1;
    a += __shfl_xor(a, 32);
    float ps = a * aw_s2[f], pd = a * aw_d2[f];
#pragma unroll
    for (int m2 = 1; m2 < 32; m2 <<= 1) { ps += __shfl_xor(ps, m2); pd += __shfl_xor(pd, m2); }
    if (ln < 32) xw2h[n * 32 + f] = __float2half_rn(a);
    if (ln == 0) { as2[n] = ps; adi[2 * n] = pd; }
}

// K6: conv2 gather, edge-parallel, half2 payload; writes 1/den into adi[2n+1].
__global__ __launch_bounds__(256) void k6_conv2(
    const int* __restrict__ offs, const int* __restrict__ edata,
    const __half2* __restrict__ xw2h2, const float* __restrict__ as2,
    float* __restrict__ adi, const float* __restrict__ b2,
    float* __restrict__ pool_part) {
    __shared__ float2 psum[4][16];
    int sub = threadIdx.x >> 5, f = threadIdx.x & 31;
    int f2 = f & 15, g = f >> 4;
    int n = blockIdx.x * 8 + sub;           // grid exact: 12500*8 = NN
    float ad = adi[2 * n];
    float den = 0.f, accx = 0.f, accy = 0.f;
    int beg = offs[n], end = offs[n + 1];
    for (int base = beg; base < end; base += 32) {
        int j = base + f;
        int src = 0;
        float ex = 0.f;
        if (j < end) {
            src = edata[j];                          // coalesced
            ex = __expf(lrelu(as2[src] + ad));       // 32 exps in parallel
        }
        den += ex;
        int cnt = min(32, end - base);
        for (int k2 = 0; k2 < cnt; k2 += 2) {
            int ki = k2 + g;                         // group g takes edge k2+g
            int   sk = __shfl(src, ki, 32);
            float ek = __shfl(ex, ki, 32);
            if (ki < cnt) {                          // explicit tail guard
                float2 fv = __half22float2(xw2h2[sk * 16 + f2]);
                accx += ek * fv.x;
                accy += ek * fv.y;
            }
        }
    }
#pragma unroll
    for (int m = 1; m < 32; m <<= 1) den += __shfl_xor(den, m, 32);
    float inv = 1.f / (den + EPSI);
    if (f == 0) adi[2 * n + 1] = inv;
    // combine the two edge-groups (same features, disjoint edges)
    accx += __shfl_xor(accx, 16, 32);
    accy += __shfl_xor(accy, 16, 32);
    float vx = accx * inv + b2[2 * f2];
    float vy = accy * inv + b2[2 * f2 + 1];
    vx = vx > 0.f ? vx : (__expf(vx) - 1.f);
    vy = vy > 0.f ? vy : (__expf(vy) - 1.f);
    // combine the wave's two nodes
    vx += __shfl_xor(vx, 32);
    vy += __shfl_xor(vy, 32);
    int wv = threadIdx.x >> 6;
    if ((threadIdx.x & 63) < 16) psum[wv][f2] = make_float2(vx, vy);
    __syncthreads();
    if (threadIdx.x < 16) {
        float2 a0 = psum[0][threadIdx.x], a1 = psum[1][threadIdx.x];
        float2 a2 = psum[2][threadIdx.x], a3 = psum[3][threadIdx.x];
        ((float2*)pool_part)[blockIdx.x * 16 + threadIdx.x] =
            make_float2(a0.x + a1.x + a2.x + a3.x, a0.y + a1.y + a2.y + a3.y);
    }
}

// K7: attn in COO order; single float2 gather for (ad2, 1/den) per dst
__global__ void k7_attn(const int* __restrict__ ei, const float* __restrict__ as2,
                        const float* __restrict__ adi, float* __restrict__ attn) {
    int e = blockIdx.x * 256 + threadIdx.x;
    if (e >= ET) return;
    int s_, d_;
    if (e < NE) { s_ = ei[e]; d_ = ei[NE + e]; } else { s_ = d_ = e - NE; }
    float2 av = *(const float2*)(adi + 2 * d_);
    attn[e] = __expf(lrelu(as2[s_] + av.x)) * av.y;
}

// K8: reduce pool partials (elu+bias already applied in k6)
__global__ void k8_pool(const float* __restrict__ pool_part, float* __restrict__ pool) {
    int tid = threadIdx.x;
    int f = tid & 31;
    float acc = 0.f;
    int st = gridDim.x * 256;
    for (int i = blockIdx.x * 256 + tid; i < 12500 * 32; i += st) acc += pool_part[i];
    acc += __shfl_xor(acc, 32);
    if ((tid & 63) < 32) unsafeAtomicAdd(&pool[f], acc);
}

// K9: logits
__global__ void k9_logits(const float* __restrict__ pool, const float* __restrict__ lin_w,
                          const float* __restrict__ lin_b, float* __restrict__ out) {
    int j = threadIdx.x;
    if (j < 2) {
        float s = 0.f;
        for (int f = 0; f < 32; f++) s += (pool[f] * (1.0f / NN)) * lin_w[f * 2 + j];
        out[j] = s + lin_b[j];
    }
}

extern "C" void kernel_launch(void* const* d_in, const int* in_sizes, int n_in,
                              void* d_out, int out_size, void* d_ws, size_t ws_size,
                              hipStream_t stream) {
    const float* x    = (const float*)d_in[0];
    const int*   ei   = (const int*)d_in[1];
    const float* W1   = (const float*)d_in[2];
    const float* aS1  = (const float*)d_in[3];
    const float* aD1  = (const float*)d_in[4];
    const float* b1   = (const float*)d_in[5];
    const float* W2   = (const float*)d_in[6];
    const float* aS2  = (const float*)d_in[7];
    const float* aD2  = (const float*)d_in[8];
    const float* b2   = (const float*)d_in[9];
    const float* linw = (const float*)d_in[10];
    const float* linb = (const float*)d_in[11];

    float*          ws    = (float*)d_ws;
    float*          as2   = ws + OFF_AS2;
    float*          adi   = ws + OFF_ADI;
    __half*         xw2h  = (__half*)(ws + OFF_XW2H);
    int*            offs  = (int*)(ws + OFF_OFFS);
    unsigned short* rank  = (unsigned short*)(ws + OFF_RANK);
    int*            ed    = (int*)(ws + OFF_EDATA);
    float*          ppart = ws + OFF_POOLPART;
    int*            deg   = (int*)(ws + OFF_DEG);
    float*          pool  = ws + OFF_POOL;
    int*            bsum  = (int*)(ws + OFF_BSUM);

    float* logits = (float*)d_out;
    float* attn   = (float*)d_out + 2;

    kz<<<98, 256, 0, stream>>>((float4*)(ws + ZERO_START), ZERO_N4);
    kc1_deg<<<(ET + 255) / 256, 256, 0, stream>>>(ei, deg, rank);
    kc2a<<<SCAN_NB, 256, 0, stream>>>(deg, bsum);
    kc2c<<<SCAN_NB, 256, 0, stream>>>(deg, bsum, offs);
    kc3_fill<<<(ET + 255) / 256, 256, 0, stream>>>(ei, offs, rank, ed);
    k4ab<<<NN / 4, 256, 0, stream>>>(offs, ed, x, aS1, aD1, W1, b1, W2,
                                     aS2, aD2, xw2h, as2, adi);
    k6_conv2<<<NN / 8, 256, 0, stream>>>(offs, ed, (const __half2*)xw2h, as2, adi,
                                         b2, ppart);
    k7_attn<<<(ET + 255) / 256, 256, 0, stream>>>(ei, as2, adi, attn);
    k8_pool<<<256, 256, 0, stream>>>(ppart, pool);
    k9_logits<<<1, 64, 0, stream>>>(pool, linw, linb, logits);
}

// Round 23
// 262.007 us; speedup vs baseline: 1.5881x; 1.5881x over previous
//
#include <hip/hip_runtime.h>
#include <hip/hip_bf16.h>
#include <hip/hip_fp16.h>

// Problem constants (fixed by reference setup_inputs)
#define NN 100000
#define NE 1600000
#define ET 1700000   // NE + NN self loops
#define NEG_SLOPE 0.2f
#define EPSI 1e-16f

#define SCAN_NB 98
#define DEG_PAD (SCAN_NB * 1024)   // 100352

// Workspace layout (4-byte element offsets). Total ~25 MB.
#define OFF_XA       32        // [NN*8] packed {x[4], as1[4]} rows (byte 128, 32B aligned)
#define OFF_AD1      800032    // [NN*4]
#define OFF_AS2      1200032   // [NN]
#define OFF_ADI      1300032   // [NN float2: .x=ad2, .y=1/den2] (byte 5200128, 8B aligned)
#define OFF_XW2H     1500032   // [NN*32 halfs = NN*16 floats]
#define OFF_OFFS     3100032   // [NN+1] int
#define OFF_RANK     3200034   // [ET ushort = 850000 floats]
#define OFF_EDATA    4050034   // [ET] int
#define OFF_POOLPART 5750036   // [12500*32] (8B aligned)
#define OFF_DEG      6150036   // [DEG_PAD] int (byte 24600144, 16B aligned) -- zero zone
#define OFF_POOL     6250388   // [64]
#define OFF_BSUM     6250452   // [112]
#define ZERO_START   OFF_DEG
#define ZERO_N4      ((DEG_PAD + 64) / 4)   // 25104 float4 (deg + pool)

__device__ __forceinline__ float lrelu(float v) { return v > 0.f ? v : NEG_SLOPE * v; }

// K1: per-block wf fold (tiny) + zero-slice of deg/pool + write packed xa + ad1.
__global__ __launch_bounds__(256) void k1_att1(
    const float* __restrict__ x, const float* __restrict__ W1,
    const float* __restrict__ aS1, const float* __restrict__ aD1,
    float* __restrict__ xa, float* __restrict__ ad1, float4* __restrict__ zz) {
    __shared__ float wfl[32];
    int t = threadIdx.x;
    if (t < 32) {   // wf[k*4+h]: fold W1 with att vectors (1024 FLOP/block, free)
        int u = t & 15, k = u >> 2, h = u & 3;
        const float* av = (t < 16) ? aS1 : aD1;
        float s = 0.f;
        for (int f = 0; f < 32; f++) s += W1[k * 128 + h * 32 + f] * av[h * 32 + f];
        wfl[t] = s;
    }
    __syncthreads();
    int gid = blockIdx.x * 256 + t;
    if (gid < ZERO_N4) zz[gid] = make_float4(0.f, 0.f, 0.f, 0.f);   // deg + pool
    int n = gid;
    if (n >= NN) return;
    float4 xv = *(const float4*)(x + n * 4);
    float* xr = xa + n * 8;
    *(float4*)xr = xv;
#pragma unroll
    for (int h = 0; h < 4; h++) {
        xr[4 + h] = xv.x * wfl[h] + xv.y * wfl[4 + h] + xv.z * wfl[8 + h] + xv.w * wfl[12 + h];
        ad1[n * 4 + h] = xv.x * wfl[16 + h] + xv.y * wfl[20 + h] + xv.z * wfl[24 + h] + xv.w * wfl[28 + h];
    }
}

// CSR: degree histogram; atomic return value IS the edge's rank (max degree << 65536)
__global__ void kc1_deg(const int* __restrict__ ei, int* __restrict__ deg,
                        unsigned short* __restrict__ rank) {
    int e = blockIdx.x * 256 + threadIdx.x;
    if (e >= ET) return;
    int d_ = (e < NE) ? ei[NE + e] : (e - NE);
    rank[e] = (unsigned short)atomicAdd(&deg[d_], 1);
}

// Scan phase A: per-block (1024 elems) sums
__global__ void kc2a(const int* __restrict__ deg, int* __restrict__ bsum) {
    __shared__ int ws_[4];
    int b = blockIdx.x, t = threadIdx.x;
    int4 d = *(const int4*)(deg + b * 1024 + t * 4);
    int s = d.x + d.y + d.z + d.w;
#pragma unroll
    for (int m = 1; m < 64; m <<= 1) s += __shfl_xor(s, m);
    if ((t & 63) == 0) ws_[t >> 6] = s;
    __syncthreads();
    if (t == 0) bsum[b] = ws_[0] + ws_[1] + ws_[2] + ws_[3];
}

// Scan phase C: every block scans the 98 block sums, then intra-block
__global__ void kc2c(const int* __restrict__ deg, const int* __restrict__ bsum,
                     int* __restrict__ offs) {
    __shared__ int bs[128];
    __shared__ int ts[256];
    int b = blockIdx.x, t = threadIdx.x;
    if (t < 128) bs[t] = (t < SCAN_NB) ? bsum[t] : 0;
    __syncthreads();
    for (int off = 1; off < 128; off <<= 1) {
        int u = (t >= off && t < 128) ? bs[t - off] : 0;
        __syncthreads();
        if (t < 128) bs[t] += u;
        __syncthreads();
    }
    int bpre = (b == 0) ? 0 : bs[b - 1];
    int base = b * 1024 + t * 4;
    int4 d = *(const int4*)(deg + base);
    int s = d.x + d.y + d.z + d.w;
    ts[t] = s;
    __syncthreads();
    for (int off = 1; off < 256; off <<= 1) {
        int u = (t >= off) ? ts[t - off] : 0;
        __syncthreads();
        ts[t] += u;
        __syncthreads();
    }
    int r = bpre + ((t == 0) ? 0 : ts[t - 1]);
    if (base < NN)     offs[base] = r;     r += d.x;
    if (base + 1 < NN) offs[base + 1] = r; r += d.y;
    if (base + 2 < NN) offs[base + 2] = r; r += d.z;
    if (base + 3 < NN) offs[base + 3] = r;
    if (b == 0 && t == 0) offs[NN] = bs[SCAN_NB - 1];   // == ET
}

// CSR fill: NO atomic — position = offs[dst] + rank[e]
__global__ void kc3_fill(const int* __restrict__ ei, const int* __restrict__ offs,
                         const unsigned short* __restrict__ rank, int* __restrict__ edata) {
    int e = blockIdx.x * 256 + threadIdx.x;
    if (e >= ET) return;
    int s_, d_;
    if (e < NE) { s_ = ei[e]; d_ = ei[NE + e]; } else { s_ = d_ = e - NE; }
    edata[offs[d_] + (int)rank[e]] = s_;
}

// K4AB: fused conv1 gather + dense. Gather reads packed xa rows (x + as1 in ONE
// 64B line per edge). W2 staged transposed in LDS (thrash-immune). All fp32.
__global__ __launch_bounds__(256) void k4ab(
    const int* __restrict__ offs, const int* __restrict__ edata,
    const float* __restrict__ xa, const float* __restrict__ ad1,
    const float* __restrict__ W1, const float* __restrict__ b1,
    const float* __restrict__ W2, const float* __restrict__ aw_s2,
    const float* __restrict__ aw_d2, __half* __restrict__ xw2h,
    float* __restrict__ as2, float* __restrict__ adi) {
    __shared__ float w2t[32][132];          // transposed W2, padded (16.9 KB)
    __shared__ float hs[4][128];
    int tid = threadIdx.x;
    int wv = tid >> 6, ln = tid & 63;
    int n = blockIdx.x * 4 + wv;            // grid exact: 25000*4 = NN
    // ---- stage W2^T into LDS (coalesced global reads; issued before gather) ----
    {
        int sf = tid & 31, sk0 = (tid >> 5) * 16;
#pragma unroll
        for (int j = 0; j < 16; j++)
            w2t[sf][sk0 + j] = W2[(sk0 + j) * 32 + sf];
    }
    // ---- gather phase (packed xa: one line per edge) ----
    int hq = ln & 3, p = ln >> 2;
    float ad = ad1[n * 4 + hq];
    float z0 = 0.f, z1 = 0.f, z2 = 0.f, z3 = 0.f, den = 0.f;
    int beg = offs[n], end = offs[n + 1];
    for (int j = beg + p; j < end; j += 16) {
        int src = edata[j];
        const float* xr = xa + src * 8;
        float4 xv = *(const float4*)xr;
        float ex = __expf(lrelu(xr[4 + hq] + ad));   // same 64B line as xv
        den += ex;
        z0 += ex * xv.x; z1 += ex * xv.y; z2 += ex * xv.z; z3 += ex * xv.w;
    }
#pragma unroll
    for (int m = 4; m <= 32; m <<= 1) {
        den += __shfl_xor(den, m);
        z0 += __shfl_xor(z0, m); z1 += __shfl_xor(z1, m);
        z2 += __shfl_xor(z2, m); z3 += __shfl_xor(z3, m);
    }
    float inv = 1.f / (den + EPSI);
    float v0 = z0 * inv, v1 = z1 * inv, v2 = z2 * inv, v3 = z3 * inv;
    // ---- W1 + elu (msg via shfl: head h lives in lane h) ----
    int f0 = ln * 2, h = ln >> 4;
    float mx = __shfl(v0, h), my = __shfl(v1, h), mz = __shfl(v2, h), mw = __shfl(v3, h);
    float h0 = mx * W1[f0]     + my * W1[128 + f0]     + mz * W1[256 + f0]     + mw * W1[384 + f0]     + b1[f0];
    float h1 = mx * W1[f0 + 1] + my * W1[128 + f0 + 1] + mz * W1[256 + f0 + 1] + mw * W1[384 + f0 + 1] + b1[f0 + 1];
    h0 = h0 > 0.f ? h0 : (__expf(h0) - 1.f);
    h1 = h1 > 0.f ? h1 : (__expf(h1) - 1.f);
    hs[wv][f0] = h0; hs[wv][f0 + 1] = h1;
    __syncthreads();                        // covers w2t staging + hs
    // ---- dense: a[f] = sum_k h[k]*W2[k][f]; half splits k; LDS b128 reads ----
    int f = ln & 31, kb = (ln >> 5) * 64;
    const float* hrow = &hs[wv][kb];
    const float* wrow = &w2t[f][kb];
    float a0 = 0.f, a1 = 0.f;
#pragma unroll
    for (int k = 0; k < 64; k += 4) {
        float4 hv  = *(const float4*)(hrow + k);
        float4 wv4 = *(const float4*)(wrow + k);
        a0 += hv.x * wv4.x + hv.y * wv4.y;
        a1 += hv.z * wv4.z + hv.w * wv4.w;
    }
    float a = a0 + a1;
    a += __shfl_xor(a, 32);
    float ps = a * aw_s2[f], pd = a * aw_d2[f];
#pragma unroll
    for (int m2 = 1; m2 < 32; m2 <<= 1) { ps += __shfl_xor(ps, m2); pd += __shfl_xor(pd, m2); }
    if (ln < 32) xw2h[n * 32 + f] = __float2half_rn(a);
    if (ln == 0) { as2[n] = ps; adi[2 * n] = pd; }
}

// K6: conv2 gather, edge-parallel, half2 payload; writes 1/den into adi[2n+1].
__global__ __launch_bounds__(256) void k6_conv2(
    const int* __restrict__ offs, const int* __restrict__ edata,
    const __half2* __restrict__ xw2h2, const float* __restrict__ as2,
    float* __restrict__ adi, const float* __restrict__ b2,
    float* __restrict__ pool_part) {
    __shared__ float2 psum[4][16];
    int sub = threadIdx.x >> 5, f = threadIdx.x & 31;
    int f2 = f & 15, g = f >> 4;
    int n = blockIdx.x * 8 + sub;           // grid exact: 12500*8 = NN
    float ad = adi[2 * n];
    float den = 0.f, accx = 0.f, accy = 0.f;
    int beg = offs[n], end = offs[n + 1];
    for (int base = beg; base < end; base += 32) {
        int j = base + f;
        int src = 0;
        float ex = 0.f;
        if (j < end) {
            src = edata[j];                          // coalesced
            ex = __expf(lrelu(as2[src] + ad));       // 32 exps in parallel
        }
        den += ex;
        int cnt = min(32, end - base);
        for (int k2 = 0; k2 < cnt; k2 += 2) {
            int ki = k2 + g;                         // group g takes edge k2+g
            int   sk = __shfl(src, ki, 32);
            float ek = __shfl(ex, ki, 32);
            if (ki < cnt) {                          // explicit tail guard
                float2 fv = __half22float2(xw2h2[sk * 16 + f2]);
                accx += ek * fv.x;
                accy += ek * fv.y;
            }
        }
    }
#pragma unroll
    for (int m = 1; m < 32; m <<= 1) den += __shfl_xor(den, m, 32);
    float inv = 1.f / (den + EPSI);
    if (f == 0) adi[2 * n + 1] = inv;
    // combine the two edge-groups (same features, disjoint edges)
    accx += __shfl_xor(accx, 16, 32);
    accy += __shfl_xor(accy, 16, 32);
    float vx = accx * inv + b2[2 * f2];
    float vy = accy * inv + b2[2 * f2 + 1];
    vx = vx > 0.f ? vx : (__expf(vx) - 1.f);
    vy = vy > 0.f ? vy : (__expf(vy) - 1.f);
    // combine the wave's two nodes
    vx += __shfl_xor(vx, 32);
    vy += __shfl_xor(vy, 32);
    int wv = threadIdx.x >> 6;
    if ((threadIdx.x & 63) < 16) psum[wv][f2] = make_float2(vx, vy);
    __syncthreads();
    if (threadIdx.x < 16) {
        float2 a0 = psum[0][threadIdx.x], a1 = psum[1][threadIdx.x];
        float2 a2 = psum[2][threadIdx.x], a3 = psum[3][threadIdx.x];
        ((float2*)pool_part)[blockIdx.x * 16 + threadIdx.x] =
            make_float2(a0.x + a1.x + a2.x + a3.x, a0.y + a1.y + a2.y + a3.y);
    }
}

// K7: attn in COO order; single float2 gather for (ad2, 1/den) per dst
__global__ void k7_attn(const int* __restrict__ ei, const float* __restrict__ as2,
                        const float* __restrict__ adi, float* __restrict__ attn) {
    int e = blockIdx.x * 256 + threadIdx.x;
    if (e >= ET) return;
    int s_, d_;
    if (e < NE) { s_ = ei[e]; d_ = ei[NE + e]; } else { s_ = d_ = e - NE; }
    float2 av = *(const float2*)(adi + 2 * d_);
    attn[e] = __expf(lrelu(as2[s_] + av.x)) * av.y;
}

// K8: reduce pool partials (elu+bias already applied in k6)
__global__ void k8_pool(const float* __restrict__ pool_part, float* __restrict__ pool) {
    int tid = threadIdx.x;
    int f = tid & 31;
    float acc = 0.f;
    int st = gridDim.x * 256;
    for (int i = blockIdx.x * 256 + tid; i < 12500 * 32; i += st) acc += pool_part[i];
    acc += __shfl_xor(acc, 32);
    if ((tid & 63) < 32) unsafeAtomicAdd(&pool[f], acc);
}

// K9: logits
__global__ void k9_logits(const float* __restrict__ pool, const float* __restrict__ lin_w,
                          const float* __restrict__ lin_b, float* __restrict__ out) {
    int j = threadIdx.x;
    if (j < 2) {
        float s = 0.f;
        for (int f = 0; f < 32; f++) s += (pool[f] * (1.0f / NN)) * lin_w[f * 2 + j];
        out[j] = s + lin_b[j];
    }
}

extern "C" void kernel_launch(void* const* d_in, const int* in_sizes, int n_in,
                              void* d_out, int out_size, void* d_ws, size_t ws_size,
                              hipStream_t stream) {
    const float* x    = (const float*)d_in[0];
    const int*   ei   = (const int*)d_in[1];
    const float* W1   = (const float*)d_in[2];
    const float* aS1  = (const float*)d_in[3];
    const float* aD1  = (const float*)d_in[4];
    const float* b1   = (const float*)d_in[5];
    const float* W2   = (const float*)d_in[6];
    const float* aS2  = (const float*)d_in[7];
    const float* aD2  = (const float*)d_in[8];
    const float* b2   = (const float*)d_in[9];
    const float* linw = (const float*)d_in[10];
    const float* linb = (const float*)d_in[11];

    float*          ws    = (float*)d_ws;
    float*          xa    = ws + OFF_XA;
    float*          ad1   = ws + OFF_AD1;
    float*          as2   = ws + OFF_AS2;
    float*          adi   = ws + OFF_ADI;
    __half*         xw2h  = (__half*)(ws + OFF_XW2H);
    int*            offs  = (int*)(ws + OFF_OFFS);
    unsigned short* rank  = (unsigned short*)(ws + OFF_RANK);
    int*            ed    = (int*)(ws + OFF_EDATA);
    float*          ppart = ws + OFF_POOLPART;
    int*            deg   = (int*)(ws + OFF_DEG);
    float*          pool  = ws + OFF_POOL;
    int*            bsum  = (int*)(ws + OFF_BSUM);

    float* logits = (float*)d_out;
    float* attn   = (float*)d_out + 2;

    k1_att1<<<(NN + 255) / 256, 256, 0, stream>>>(x, W1, aS1, aD1, xa, ad1,
                                                  (float4*)(ws + ZERO_START));
    kc1_deg<<<(ET + 255) / 256, 256, 0, stream>>>(ei, deg, rank);
    kc2a<<<SCAN_NB, 256, 0, stream>>>(deg, bsum);
    kc2c<<<SCAN_NB, 256, 0, stream>>>(deg, bsum, offs);
    kc3_fill<<<(ET + 255) / 256, 256, 0, stream>>>(ei, offs, rank, ed);
    k4ab<<<NN / 4, 256, 0, stream>>>(offs, ed, xa, ad1, W1, b1, W2,
                                     aS2, aD2, xw2h, as2, adi);
    k6_conv2<<<NN / 8, 256, 0, stream>>>(offs, ed, (const __half2*)xw2h, as2, adi,
                                         b2, ppart);
    k7_attn<<<(ET + 255) / 256, 256, 0, stream>>>(ei, as2, adi, attn);
    k8_pool<<<256, 256, 0, stream>>>(ppart, pool);
    k9_logits<<<1, 64, 0, stream>>>(pool, linw, linb, logits);
}